// Round 1
// baseline (1932.443 us; speedup 1.0000x reference)
//
#include <hip/hip_runtime.h>
#include <hip/hip_bf16.h>

// Problem constants
#define B_    32
#define C_    512
#define S_    1024      // H*W = 32*32
#define G_    32        // groups
#define CPG_  16        // channels per group
#define C3_   1536      // 3*C
#define EPS_  1e-5f
#define SCALE_ 0.044194173824159216f   // 1/sqrt(512)

// ---------- helpers ----------
__device__ __forceinline__ float bf2f(unsigned short u) {
    union { unsigned int i; float f; } v;
    v.i = ((unsigned int)u) << 16;
    return v.f;
}
__device__ __forceinline__ unsigned short f2bf(float f) {
    union { float f; unsigned int i; } v;
    v.f = f;
    unsigned int r = v.i + 0x7fffu + ((v.i >> 16) & 1u);  // RNE
    return (unsigned short)(r >> 16);
}

// ---------- Kernel A: group-norm statistics ----------
// grid = B_*G_ blocks, 256 threads. Each block reduces 16 ch x 1024 spatial.
__global__ __launch_bounds__(256) void gn_stats(const float* __restrict__ x,
                                                float2* __restrict__ stats) {
    const size_t base = (size_t)blockIdx.x * (CPG_ * S_);
    const float4* xp = (const float4*)(x + base);
    float s = 0.f, ss = 0.f;
    for (int i = threadIdx.x; i < (CPG_ * S_) / 4; i += 256) {
        float4 v = xp[i];
        s  += v.x + v.y + v.z + v.w;
        ss += v.x * v.x + v.y * v.y + v.z * v.z + v.w * v.w;
    }
    #pragma unroll
    for (int o = 32; o; o >>= 1) { s += __shfl_down(s, o); ss += __shfl_down(ss, o); }
    __shared__ float a1[4], a2[4];
    const int wid = threadIdx.x >> 6, lane = threadIdx.x & 63;
    if (lane == 0) { a1[wid] = s; a2[wid] = ss; }
    __syncthreads();
    if (threadIdx.x == 0) {
        float S  = a1[0] + a1[1] + a1[2] + a1[3];
        float SS = a2[0] + a2[1] + a2[2] + a2[3];
        float mean = S * (1.f / 16384.f);
        float var  = SS * (1.f / 16384.f) - mean * mean;
        stats[blockIdx.x] = make_float2(mean, rsqrtf(var + EPS_));
    }
}

// ---------- Kernel B: QKV GEMM with fused group-norm ----------
// qkv[b][o][s] = bf16( sum_c w[o][c] * norm(x[b][c][s]) + bias[o] )
// grid = (16 s-tiles, 24 o-tiles, 32 b), 256 threads, 64x64 tile, BK=16.
__global__ __launch_bounds__(256) void qkv_gemm(
    const float* __restrict__ x, const float* __restrict__ gamma,
    const float* __restrict__ beta, const float* __restrict__ w,
    const float* __restrict__ bias, const float2* __restrict__ stats,
    unsigned short* __restrict__ qkv)
{
    const int b = blockIdx.z, ot = blockIdx.y, st = blockIdx.x;
    __shared__ float Ws[16][68];   // [c][o]  (K-major)
    __shared__ float Xs[16][68];   // [c][s]  (K-major)
    const int t = threadIdx.x;
    const int tx = t & 15, ty = t >> 4;
    const int o0 = ot * 64, s0 = st * 64;
    const int wo = t >> 2;           // 0..63
    const int wc = (t & 3) * 4;      // 0,4,8,12
    const int xs = t & 63;           // 0..63
    const int xc = t >> 6;           // 0..3
    const float* xb = x + (size_t)b * C_ * S_;
    float acc[4][4] = {};
    for (int c0 = 0; c0 < C_; c0 += 16) {
        float4 wv = *(const float4*)(w + (size_t)(o0 + wo) * C_ + c0 + wc);
        Ws[wc + 0][wo] = wv.x;
        Ws[wc + 1][wo] = wv.y;
        Ws[wc + 2][wo] = wv.z;
        Ws[wc + 3][wo] = wv.w;
        #pragma unroll
        for (int i = 0; i < 4; i++) {
            int cr = xc + i * 4;         // 0..15
            int c  = c0 + cr;
            float2 mv = stats[b * G_ + (c >> 4)];
            float a  = mv.y * gamma[c];
            float bb = beta[c] - mv.x * a;
            Xs[cr][xs] = a * xb[(size_t)c * S_ + s0 + xs] + bb;
        }
        __syncthreads();
        #pragma unroll
        for (int kk = 0; kk < 16; kk++) {
            float4 av = *(const float4*)&Ws[kk][ty * 4];
            float4 bv = *(const float4*)&Xs[kk][tx * 4];
            float a4[4] = {av.x, av.y, av.z, av.w};
            float b4[4] = {bv.x, bv.y, bv.z, bv.w};
            #pragma unroll
            for (int i = 0; i < 4; i++)
                #pragma unroll
                for (int j = 0; j < 4; j++)
                    acc[i][j] += a4[i] * b4[j];
        }
        __syncthreads();
    }
    unsigned short* op = qkv + (size_t)b * C3_ * S_;
    #pragma unroll
    for (int i = 0; i < 4; i++) {
        int o = o0 + ty * 4 + i;
        float bi = bias[o];
        #pragma unroll
        for (int j = 0; j < 4; j++)
            op[(size_t)o * S_ + s0 + tx * 4 + j] = f2bf(acc[i][j] + bi);
    }
}

// ---------- Kernel C: attention scores ----------
// attn[b][i][j] = bf16( SCALE * sum_c Q[c][i] * K[c][j] )
// grid = (16 j-tiles, 16 i-tiles, 32 b)
__global__ __launch_bounds__(256) void scores_gemm(const unsigned short* __restrict__ qkv,
                                                   unsigned short* __restrict__ attn)
{
    const int b = blockIdx.z, it = blockIdx.y, jt = blockIdx.x;
    __shared__ float Qs[16][68], Ks[16][68];
    const unsigned short* Q = qkv + (size_t)b * C3_ * S_;
    const unsigned short* K = Q + (size_t)C_ * S_;
    const int t = threadIdx.x, tx = t & 15, ty = t >> 4;
    const int lc  = t >> 4;           // 0..15 staging row
    const int ls4 = (t & 15) * 4;     // staging col*4
    const int i0 = it * 64, j0 = jt * 64;
    float acc[4][4] = {};
    for (int c0 = 0; c0 < C_; c0 += 16) {
        ushort4 qv = *(const ushort4*)(Q + (size_t)(c0 + lc) * S_ + i0 + ls4);
        ushort4 kv = *(const ushort4*)(K + (size_t)(c0 + lc) * S_ + j0 + ls4);
        Qs[lc][ls4 + 0] = bf2f(qv.x); Qs[lc][ls4 + 1] = bf2f(qv.y);
        Qs[lc][ls4 + 2] = bf2f(qv.z); Qs[lc][ls4 + 3] = bf2f(qv.w);
        Ks[lc][ls4 + 0] = bf2f(kv.x); Ks[lc][ls4 + 1] = bf2f(kv.y);
        Ks[lc][ls4 + 2] = bf2f(kv.z); Ks[lc][ls4 + 3] = bf2f(kv.w);
        __syncthreads();
        #pragma unroll
        for (int kk = 0; kk < 16; kk++) {
            float4 av = *(const float4*)&Qs[kk][ty * 4];
            float4 bv = *(const float4*)&Ks[kk][tx * 4];
            float a4[4] = {av.x, av.y, av.z, av.w};
            float b4[4] = {bv.x, bv.y, bv.z, bv.w};
            #pragma unroll
            for (int i = 0; i < 4; i++)
                #pragma unroll
                for (int j = 0; j < 4; j++)
                    acc[i][j] += a4[i] * b4[j];
        }
        __syncthreads();
    }
    unsigned short* ap = attn + (size_t)b * S_ * S_;
    #pragma unroll
    for (int i = 0; i < 4; i++)
        #pragma unroll
        for (int j = 0; j < 4; j++)
            ap[(size_t)(i0 + ty * 4 + i) * S_ + j0 + tx * 4 + j] = f2bf(acc[i][j] * SCALE_);
}

// ---------- Kernel D: row softmax (in place, bf16) ----------
// grid = B_*S_ blocks of 256 threads, each block = one row of 1024.
__global__ __launch_bounds__(256) void softmax_rows(unsigned short* __restrict__ attn) {
    unsigned short* p = attn + (size_t)blockIdx.x * S_;
    const int t = threadIdx.x;
    ushort4 uv = *(const ushort4*)(p + t * 4);
    float v0 = bf2f(uv.x), v1 = bf2f(uv.y), v2 = bf2f(uv.z), v3 = bf2f(uv.w);
    float m = fmaxf(fmaxf(v0, v1), fmaxf(v2, v3));
    #pragma unroll
    for (int o = 32; o; o >>= 1) m = fmaxf(m, __shfl_down(m, o));
    __shared__ float lm[4], lsum[4];
    const int wid = t >> 6, lane = t & 63;
    if (lane == 0) lm[wid] = m;
    __syncthreads();
    m = fmaxf(fmaxf(lm[0], lm[1]), fmaxf(lm[2], lm[3]));
    float e0 = __expf(v0 - m), e1 = __expf(v1 - m), e2 = __expf(v2 - m), e3 = __expf(v3 - m);
    float s = e0 + e1 + e2 + e3;
    #pragma unroll
    for (int o = 32; o; o >>= 1) s += __shfl_down(s, o);
    if (lane == 0) lsum[wid] = s;
    __syncthreads();
    float T = lsum[0] + lsum[1] + lsum[2] + lsum[3];
    float r = __frcp_rn(T);
    ushort4 ov;
    ov.x = f2bf(e0 * r); ov.y = f2bf(e1 * r); ov.z = f2bf(e2 * r); ov.w = f2bf(e3 * r);
    *(ushort4*)(p + t * 4) = ov;
}

// ---------- Kernel E: P*V ----------
// O[b][c][i] = bf16( sum_j attn[i][j] * V[c][j] )   (reduction over contiguous j)
// grid = (16 i-tiles, 8 c-tiles, 32 b)
__global__ __launch_bounds__(256) void pv_gemm(const unsigned short* __restrict__ qkv,
                                               const unsigned short* __restrict__ attn,
                                               unsigned short* __restrict__ O)
{
    const int b = blockIdx.z, ct = blockIdx.y, it = blockIdx.x;
    __shared__ float Vs[16][68], As[16][68];   // [j][c], [j][i]  (K-major)
    const unsigned short* V = qkv + ((size_t)b * C3_ + 2 * C_) * S_;
    const unsigned short* A = attn + (size_t)b * S_ * S_;
    const int t = threadIdx.x, tx = t & 15, ty = t >> 4;
    const int r  = t >> 2;          // 0..63 tile row
    const int jj = (t & 3) * 4;     // 0,4,8,12
    const int c0 = ct * 64, i0 = it * 64;
    float acc[4][4] = {};
    for (int j0 = 0; j0 < S_; j0 += 16) {
        ushort4 vv = *(const ushort4*)(V + (size_t)(c0 + r) * S_ + j0 + jj);
        ushort4 av = *(const ushort4*)(A + (size_t)(i0 + r) * S_ + j0 + jj);
        Vs[jj + 0][r] = bf2f(vv.x); Vs[jj + 1][r] = bf2f(vv.y);
        Vs[jj + 2][r] = bf2f(vv.z); Vs[jj + 3][r] = bf2f(vv.w);
        As[jj + 0][r] = bf2f(av.x); As[jj + 1][r] = bf2f(av.y);
        As[jj + 2][r] = bf2f(av.z); As[jj + 3][r] = bf2f(av.w);
        __syncthreads();
        #pragma unroll
        for (int kk = 0; kk < 16; kk++) {
            float4 cv = *(const float4*)&Vs[kk][ty * 4];
            float4 iv = *(const float4*)&As[kk][tx * 4];
            float a4[4] = {cv.x, cv.y, cv.z, cv.w};
            float b4[4] = {iv.x, iv.y, iv.z, iv.w};
            #pragma unroll
            for (int i = 0; i < 4; i++)
                #pragma unroll
                for (int j = 0; j < 4; j++)
                    acc[i][j] += a4[i] * b4[j];
        }
        __syncthreads();
    }
    unsigned short* Ob = O + (size_t)b * C_ * S_;
    #pragma unroll
    for (int i = 0; i < 4; i++)
        #pragma unroll
        for (int j = 0; j < 4; j++)
            Ob[(size_t)(c0 + ty * 4 + i) * S_ + i0 + tx * 4 + j] = f2bf(acc[i][j]);
}

// ---------- Kernel F: output projection + residual ----------
// out[b][o][s] = sum_c w_out[o][c] * O[b][c][s] + b_out[o] + x[b][o][s]
// grid = (16 s-tiles, 8 o-tiles, 32 b)
__global__ __launch_bounds__(256) void out_gemm(const unsigned short* __restrict__ Obuf,
                                                const float* __restrict__ w,
                                                const float* __restrict__ bias,
                                                const float* __restrict__ x,
                                                float* __restrict__ out)
{
    const int b = blockIdx.z, ot = blockIdx.y, st = blockIdx.x;
    __shared__ float Ws[16][68], Os[16][68];
    const int t = threadIdx.x, tx = t & 15, ty = t >> 4;
    const int o0 = ot * 64, s0 = st * 64;
    const int wo = t >> 2, wc = (t & 3) * 4;
    const int lc = t >> 4, ls4 = (t & 15) * 4;
    const unsigned short* Ob = Obuf + (size_t)b * C_ * S_;
    float acc[4][4] = {};
    for (int c0 = 0; c0 < C_; c0 += 16) {
        float4 wv = *(const float4*)(w + (size_t)(o0 + wo) * C_ + c0 + wc);
        Ws[wc + 0][wo] = wv.x;
        Ws[wc + 1][wo] = wv.y;
        Ws[wc + 2][wo] = wv.z;
        Ws[wc + 3][wo] = wv.w;
        ushort4 ov = *(const ushort4*)(Ob + (size_t)(c0 + lc) * S_ + s0 + ls4);
        Os[lc][ls4 + 0] = bf2f(ov.x); Os[lc][ls4 + 1] = bf2f(ov.y);
        Os[lc][ls4 + 2] = bf2f(ov.z); Os[lc][ls4 + 3] = bf2f(ov.w);
        __syncthreads();
        #pragma unroll
        for (int kk = 0; kk < 16; kk++) {
            float4 av = *(const float4*)&Ws[kk][ty * 4];
            float4 bv = *(const float4*)&Os[kk][tx * 4];
            float a4[4] = {av.x, av.y, av.z, av.w};
            float b4[4] = {bv.x, bv.y, bv.z, bv.w};
            #pragma unroll
            for (int i = 0; i < 4; i++)
                #pragma unroll
                for (int j = 0; j < 4; j++)
                    acc[i][j] += a4[i] * b4[j];
        }
        __syncthreads();
    }
    const float* xb = x + (size_t)b * C_ * S_;
    float* ob = out + (size_t)b * C_ * S_;
    #pragma unroll
    for (int i = 0; i < 4; i++) {
        int o = o0 + ty * 4 + i;
        float bi = bias[o];
        size_t base = (size_t)o * S_ + s0 + tx * 4;
        float4 xv = *(const float4*)(xb + base);
        float4 rres;
        rres.x = acc[i][0] + bi + xv.x;
        rres.y = acc[i][1] + bi + xv.y;
        rres.z = acc[i][2] + bi + xv.z;
        rres.w = acc[i][3] + bi + xv.w;
        *(float4*)(ob + base) = rres;
    }
}

// ---------- launch ----------
extern "C" void kernel_launch(void* const* d_in, const int* in_sizes, int n_in,
                              void* d_out, int out_size, void* d_ws, size_t ws_size,
                              hipStream_t stream) {
    const float* x      = (const float*)d_in[0];
    const float* gamma  = (const float*)d_in[1];
    const float* beta   = (const float*)d_in[2];
    const float* w_qkv  = (const float*)d_in[3];
    const float* b_qkv  = (const float*)d_in[4];
    const float* w_out  = (const float*)d_in[5];
    const float* b_out  = (const float*)d_in[6];
    float* out          = (float*)d_out;

    char* ws = (char*)d_ws;
    // workspace layout (bytes):
    //   qkv  bf16 [32][1536][1024] : 100663296
    //   attn bf16 [32][1024][1024] :  67108864
    //   O    bf16 [32][ 512][1024] :  33554432
    //   stats float2 [32*32]       :      8192       total ~192 MB
    unsigned short* qkv  = (unsigned short*)ws;
    unsigned short* attn = (unsigned short*)(ws + 100663296ULL);
    unsigned short* Obuf = (unsigned short*)(ws + 100663296ULL + 67108864ULL);
    float2* stats        = (float2*)(ws + 100663296ULL + 67108864ULL + 33554432ULL);

    gn_stats    <<<B_ * G_, 256, 0, stream>>>(x, stats);
    qkv_gemm    <<<dim3(16, 24, B_), 256, 0, stream>>>(x, gamma, beta, w_qkv, b_qkv, stats, qkv);
    scores_gemm <<<dim3(16, 16, B_), 256, 0, stream>>>(qkv, attn);
    softmax_rows<<<B_ * S_, 256, 0, stream>>>(attn);
    pv_gemm     <<<dim3(16, 8, B_), 256, 0, stream>>>(qkv, attn, Obuf);
    out_gemm    <<<dim3(16, 8, B_), 256, 0, stream>>>(Obuf, w_out, b_out, x, out);
}

// Round 2
// 432.702 us; speedup vs baseline: 4.4660x; 4.4660x over previous
//
#include <hip/hip_runtime.h>
#include <hip/hip_bf16.h>

#define B_    32
#define C_    512
#define S_    1024
#define G_    32
#define CPG_  16
#define C3_   1536
#define EPS_  1e-5f
#define SCALE_ 0.044194173824159216f   // 1/sqrt(512)

typedef __attribute__((ext_vector_type(4))) float  floatx4;
typedef __attribute__((ext_vector_type(8))) __bf16 bf16x8;

#define LDSW 40   // ushorts per LDS row (32 data + 8 pad = 80 B, 20 banks -> <=2-way)

__device__ __forceinline__ float bf2f(unsigned short u) {
    union { unsigned int i; float f; } v; v.i = ((unsigned int)u) << 16; return v.f;
}
__device__ __forceinline__ unsigned short f2bf(float f) {
    union { float f; unsigned int i; } v; v.f = f;
    unsigned int r = v.i + 0x7fffu + ((v.i >> 16) & 1u);
    return (unsigned short)(r >> 16);
}

// ---------------- group-norm stats ----------------
__global__ __launch_bounds__(256) void gn_stats(const float* __restrict__ x,
                                                float2* __restrict__ stats) {
    const size_t base = (size_t)blockIdx.x * (CPG_ * S_);
    const float4* xp = (const float4*)(x + base);
    float s = 0.f, ss = 0.f;
    for (int i = threadIdx.x; i < (CPG_ * S_) / 4; i += 256) {
        float4 v = xp[i];
        s  += v.x + v.y + v.z + v.w;
        ss += v.x * v.x + v.y * v.y + v.z * v.z + v.w * v.w;
    }
    #pragma unroll
    for (int o = 32; o; o >>= 1) { s += __shfl_down(s, o); ss += __shfl_down(ss, o); }
    __shared__ float a1[4], a2[4];
    const int wid = threadIdx.x >> 6, lane = threadIdx.x & 63;
    if (lane == 0) { a1[wid] = s; a2[wid] = ss; }
    __syncthreads();
    if (threadIdx.x == 0) {
        float S  = a1[0] + a1[1] + a1[2] + a1[3];
        float SS = a2[0] + a2[1] + a2[2] + a2[3];
        float mean = S * (1.f / 16384.f);
        float var  = SS * (1.f / 16384.f) - mean * mean;
        stats[blockIdx.x] = make_float2(mean, rsqrtf(var + EPS_));
    }
}

// ---------------- fp32 -> bf16 convert ----------------
__global__ __launch_bounds__(256) void cast_bf16(const float* __restrict__ src,
                                                 unsigned short* __restrict__ dst) {
    int i = (blockIdx.x * 256 + threadIdx.x) * 4;
    float4 v = *(const float4*)(src + i);
    ushort4 o; o.x = f2bf(v.x); o.y = f2bf(v.y); o.z = f2bf(v.z); o.w = f2bf(v.w);
    *(ushort4*)(dst + i) = o;
}

// ---------------- normalized x, transposed to [b][s][c], bf16 ----------------
__global__ __launch_bounds__(256) void xnt_kernel(const float* __restrict__ x,
                                                  const float* __restrict__ gamma,
                                                  const float* __restrict__ beta,
                                                  const float2* __restrict__ stats,
                                                  unsigned short* __restrict__ xnt) {
    const int b = blockIdx.z, c0 = blockIdx.y * 64, s0 = blockIdx.x * 64;
    __shared__ float tile[64][65];
    const float* xb = x + (size_t)b * (C_ * S_);
    const int t = threadIdx.x, tr = t >> 4, tc4 = (t & 15) * 4;
    #pragma unroll
    for (int i = 0; i < 4; i++) {
        int r = tr + i * 16;
        int c = c0 + r;
        float2 mv = stats[b * G_ + (c >> 4)];
        float a  = mv.y * gamma[c];
        float bb = beta[c] - mv.x * a;
        float4 v = *(const float4*)(xb + (size_t)c * S_ + s0 + tc4);
        tile[r][tc4 + 0] = a * v.x + bb;
        tile[r][tc4 + 1] = a * v.y + bb;
        tile[r][tc4 + 2] = a * v.z + bb;
        tile[r][tc4 + 3] = a * v.w + bb;
    }
    __syncthreads();
    unsigned short* xo = xnt + (size_t)b * (S_ * C_);
    #pragma unroll
    for (int i = 0; i < 4; i++) {
        int sr = tr + i * 16;
        ushort4 o4;
        o4.x = f2bf(tile[tc4 + 0][sr]);
        o4.y = f2bf(tile[tc4 + 1][sr]);
        o4.z = f2bf(tile[tc4 + 2][sr]);
        o4.w = f2bf(tile[tc4 + 3][sr]);
        *(ushort4*)(xo + (size_t)(s0 + sr) * C_ + c0 + tc4) = o4;
    }
}

// ---------------- MFMA 128x128 mainloop ----------------
// C[m][n] = sum_k A[m][k]*B[n][k]; A,B bf16 K-contiguous. SWAP passes (B,A) to
// mfma so D rows index n and cols index m (free output transpose).
template<bool SWAP>
__device__ __forceinline__ void mfma_loop(const unsigned short* __restrict__ Ag, int lda,
                                          const unsigned short* __restrict__ Bg, int ldb,
                                          int K, int m0, int n0,
                                          unsigned short* ldsA, unsigned short* ldsB,
                                          floatx4 (&acc)[4][4]) {
    const int t = threadIdx.x;
    const int lane = t & 63, wave = t >> 6;
    const int wr = (wave >> 1) * 64, wc = (wave & 1) * 64;
    const int lrow = lane & 15, lq = lane >> 4;
    const int r1 = t >> 2,          k1 = (t & 3) * 8;
    const int r2 = (t + 256) >> 2,  k2 = k1;          // (t+256)&3 == t&3
    for (int k0 = 0; k0 < K; k0 += 32) {
        uint4 a1 = *(const uint4*)(Ag + (size_t)(m0 + r1) * lda + k0 + k1);
        uint4 a2 = *(const uint4*)(Ag + (size_t)(m0 + r2) * lda + k0 + k2);
        uint4 b1 = *(const uint4*)(Bg + (size_t)(n0 + r1) * ldb + k0 + k1);
        uint4 b2 = *(const uint4*)(Bg + (size_t)(n0 + r2) * ldb + k0 + k2);
        *(uint4*)(ldsA + r1 * LDSW + k1) = a1;
        *(uint4*)(ldsA + r2 * LDSW + k2) = a2;
        *(uint4*)(ldsB + r1 * LDSW + k1) = b1;
        *(uint4*)(ldsB + r2 * LDSW + k2) = b2;
        __syncthreads();
        bf16x8 af[4], bf[4];
        #pragma unroll
        for (int i = 0; i < 4; i++) {
            af[i] = *(const bf16x8*)(ldsA + (wr + i * 16 + lrow) * LDSW + lq * 8);
            bf[i] = *(const bf16x8*)(ldsB + (wc + i * 16 + lrow) * LDSW + lq * 8);
        }
        #pragma unroll
        for (int i = 0; i < 4; i++)
            #pragma unroll
            for (int j = 0; j < 4; j++) {
                if (SWAP)
                    acc[i][j] = __builtin_amdgcn_mfma_f32_16x16x32_bf16(bf[j], af[i], acc[i][j], 0, 0, 0);
                else
                    acc[i][j] = __builtin_amdgcn_mfma_f32_16x16x32_bf16(af[i], bf[j], acc[i][j], 0, 0, 0);
            }
        __syncthreads();
    }
}

#define GEMM_PROLOGUE                                                   \
    __shared__ __align__(16) unsigned short ldsA[128 * LDSW];           \
    __shared__ __align__(16) unsigned short ldsB[128 * LDSW];           \
    const int b = blockIdx.z;                                           \
    const int m0 = blockIdx.y * 128, n0 = blockIdx.x * 128;             \
    const int t = threadIdx.x, lane = t & 63, wave = t >> 6;            \
    const int wr = (wave >> 1) * 64, wc = (wave & 1) * 64;              \
    const int lrow = lane & 15, lq = lane >> 4;                         \
    floatx4 acc[4][4];                                                  \
    _Pragma("unroll") for (int i = 0; i < 4; i++)                       \
        _Pragma("unroll") for (int j = 0; j < 4; j++)                   \
            acc[i][j] = (floatx4){0.f, 0.f, 0.f, 0.f};

// ---------------- QKV projection ----------------
// A = wqkv_bf [1536][512], B = xnt[b] [1024][512].
// m-tiles 0-3 -> Q[s][c], 4-7 -> K[s][c] (transposed write), 8-11 -> V[c][s] (SWAP).
__global__ __launch_bounds__(256) void qkv_mfma(const unsigned short* __restrict__ wbf,
                                                const unsigned short* __restrict__ xnt,
                                                const float* __restrict__ bias,
                                                unsigned short* __restrict__ Qb,
                                                unsigned short* __restrict__ Kb,
                                                unsigned short* __restrict__ Vb) {
    GEMM_PROLOGUE
    const unsigned short* Bg = xnt + (size_t)b * (S_ * C_);
    if (m0 < 1024) {
        mfma_loop<false>(wbf, C_, Bg, C_, C_, m0, n0, ldsA, ldsB, acc);
        unsigned short* dst = (m0 < 512 ? Qb : Kb) + (size_t)b * (S_ * C_);
        const int osec = (m0 < 512) ? 0 : 512;
        #pragma unroll
        for (int i = 0; i < 4; i++)
            #pragma unroll
            for (int j = 0; j < 4; j++) {
                int oabs = m0 + wr + i * 16 + lq * 4;
                int s    = n0 + wc + j * 16 + lrow;
                float4 bi = *(const float4*)(bias + oabs);
                floatx4 v = acc[i][j];
                ushort4 o4;
                o4.x = f2bf(v[0] + bi.x); o4.y = f2bf(v[1] + bi.y);
                o4.z = f2bf(v[2] + bi.z); o4.w = f2bf(v[3] + bi.w);
                *(ushort4*)(dst + (size_t)s * C_ + (oabs - osec)) = o4;
            }
    } else {
        mfma_loop<true>(wbf, C_, Bg, C_, C_, m0, n0, ldsA, ldsB, acc);
        unsigned short* dst = Vb + (size_t)b * (C_ * S_);
        #pragma unroll
        for (int i = 0; i < 4; i++)
            #pragma unroll
            for (int j = 0; j < 4; j++) {
                int c  = m0 - 1024 + wr + i * 16 + lrow;   // cols index m (o)
                int sb = n0 + wc + j * 16 + lq * 4;        // rows index n (s)
                float bi = bias[1024 + c];
                floatx4 v = acc[i][j];
                ushort4 o4;
                o4.x = f2bf(v[0] + bi); o4.y = f2bf(v[1] + bi);
                o4.z = f2bf(v[2] + bi); o4.w = f2bf(v[3] + bi);
                *(ushort4*)(dst + (size_t)c * S_ + sb) = o4;
            }
    }
}

// ---------------- scores: attn[i][j] = SCALE * Q[i][:] . K[j][:] ----------------
__global__ __launch_bounds__(256) void scores_mfma(const unsigned short* __restrict__ Qb,
                                                   const unsigned short* __restrict__ Kb,
                                                   unsigned short* __restrict__ attn) {
    GEMM_PROLOGUE
    const unsigned short* Ag = Qb + (size_t)b * (S_ * C_);
    const unsigned short* Bg = Kb + (size_t)b * (S_ * C_);
    mfma_loop<false>(Ag, C_, Bg, C_, C_, m0, n0, ldsA, ldsB, acc);
    unsigned short* ap = attn + (size_t)b * (S_ * S_);
    #pragma unroll
    for (int i = 0; i < 4; i++)
        #pragma unroll
        for (int j = 0; j < 4; j++) {
            int jj = n0 + wc + j * 16 + lrow;
            int ib = m0 + wr + i * 16 + lq * 4;
            floatx4 v = acc[i][j];
            #pragma unroll
            for (int r = 0; r < 4; r++)
                ap[(size_t)(ib + r) * S_ + jj] = f2bf(v[r] * SCALE_);
        }
}

// ---------------- softmax rows (in place bf16) ----------------
__global__ __launch_bounds__(256) void softmax_rows(unsigned short* __restrict__ attn) {
    unsigned short* p = attn + (size_t)blockIdx.x * S_;
    const int t = threadIdx.x;
    ushort4 uv = *(const ushort4*)(p + t * 4);
    float v0 = bf2f(uv.x), v1 = bf2f(uv.y), v2 = bf2f(uv.z), v3 = bf2f(uv.w);
    float m = fmaxf(fmaxf(v0, v1), fmaxf(v2, v3));
    #pragma unroll
    for (int o = 32; o; o >>= 1) m = fmaxf(m, __shfl_down(m, o));
    __shared__ float lm[4], lsum[4];
    const int wid = t >> 6, lane = t & 63;
    if (lane == 0) lm[wid] = m;
    __syncthreads();
    m = fmaxf(fmaxf(lm[0], lm[1]), fmaxf(lm[2], lm[3]));
    float e0 = __expf(v0 - m), e1 = __expf(v1 - m), e2 = __expf(v2 - m), e3 = __expf(v3 - m);
    float s = e0 + e1 + e2 + e3;
    #pragma unroll
    for (int o = 32; o; o >>= 1) s += __shfl_down(s, o);
    if (lane == 0) lsum[wid] = s;
    __syncthreads();
    float T = lsum[0] + lsum[1] + lsum[2] + lsum[3];
    float r = __frcp_rn(T);
    ushort4 ov;
    ov.x = f2bf(e0 * r); ov.y = f2bf(e1 * r); ov.z = f2bf(e2 * r); ov.w = f2bf(e3 * r);
    *(ushort4*)(p + t * 4) = ov;
}

// ---------------- PV: O[i][c] = sum_j P[i][j] V[c][j] ----------------
__global__ __launch_bounds__(256) void pv_mfma(const unsigned short* __restrict__ attn,
                                               const unsigned short* __restrict__ Vb,
                                               unsigned short* __restrict__ Ob) {
    GEMM_PROLOGUE
    const unsigned short* Ag = attn + (size_t)b * (S_ * S_);
    const unsigned short* Bg = Vb + (size_t)b * (C_ * S_);
    mfma_loop<false>(Ag, S_, Bg, S_, S_, m0, n0, ldsA, ldsB, acc);
    unsigned short* op = Ob + (size_t)b * (S_ * C_);
    #pragma unroll
    for (int i = 0; i < 4; i++)
        #pragma unroll
        for (int j = 0; j < 4; j++) {
            int cc = n0 + wc + j * 16 + lrow;
            int ib = m0 + wr + i * 16 + lq * 4;
            floatx4 v = acc[i][j];
            #pragma unroll
            for (int r = 0; r < 4; r++)
                op[(size_t)(ib + r) * C_ + cc] = f2bf(v[r]);
        }
}

// ---------------- out projection + bias + residual ----------------
__global__ __launch_bounds__(256) void out_mfma(const unsigned short* __restrict__ wbf,
                                                const unsigned short* __restrict__ Ob,
                                                const float* __restrict__ bias,
                                                const float* __restrict__ x,
                                                float* __restrict__ out) {
    GEMM_PROLOGUE
    const unsigned short* Bg = Ob + (size_t)b * (S_ * C_);
    mfma_loop<false>(wbf, C_, Bg, C_, C_, m0, n0, ldsA, ldsB, acc);
    const float* xb = x + (size_t)b * (C_ * S_);
    float* ob = out + (size_t)b * (C_ * S_);
    #pragma unroll
    for (int i = 0; i < 4; i++)
        #pragma unroll
        for (int j = 0; j < 4; j++) {
            int obase = m0 + wr + i * 16 + lq * 4;
            int s     = n0 + wc + j * 16 + lrow;
            float4 bi = *(const float4*)(bias + obase);
            floatx4 v = acc[i][j];
            float bb[4] = {bi.x, bi.y, bi.z, bi.w};
            #pragma unroll
            for (int r = 0; r < 4; r++) {
                size_t idx = (size_t)(obase + r) * S_ + s;
                ob[idx] = v[r] + bb[r] + xb[idx];
            }
        }
}

// ---------------- launch ----------------
extern "C" void kernel_launch(void* const* d_in, const int* in_sizes, int n_in,
                              void* d_out, int out_size, void* d_ws, size_t ws_size,
                              hipStream_t stream) {
    const float* x      = (const float*)d_in[0];
    const float* gamma  = (const float*)d_in[1];
    const float* beta   = (const float*)d_in[2];
    const float* w_qkv  = (const float*)d_in[3];
    const float* b_qkv  = (const float*)d_in[4];
    const float* w_out  = (const float*)d_in[5];
    const float* b_out  = (const float*)d_in[6];
    float* out          = (float*)d_out;

    char* ws = (char*)d_ws;
    // layout (bytes), with safe aliasing (all kernels stream-ordered):
    //   Qb   [b][1024][512] bf16 @ 0         (32 MB)  -- dead after scores
    //   Kb   [b][1024][512] bf16 @ 32 MB     (32 MB)
    //   Vb   [b][512][1024] bf16 @ 64 MB     (32 MB)
    //   xnt  [b][1024][512] bf16 @ 96 MB     (32 MB)  -- dead after qkv
    //   attn [b][1024][1024] bf16 @ 96 MB    (64 MB)  -- aliases xnt
    //   Ob   [b][1024][512] bf16 @ 0         (32 MB)  -- aliases Qb
    //   wqkv_bf @ 160 MB, wout_bf, stats     (~2.1 MB)
    unsigned short* Qb   = (unsigned short*)(ws);
    unsigned short* Kb   = (unsigned short*)(ws + 33554432ULL);
    unsigned short* Vb   = (unsigned short*)(ws + 67108864ULL);
    unsigned short* xnt  = (unsigned short*)(ws + 100663296ULL);
    unsigned short* attn = (unsigned short*)(ws + 100663296ULL);
    unsigned short* Ob   = (unsigned short*)(ws);
    unsigned short* wqkv_bf = (unsigned short*)(ws + 167772160ULL);
    unsigned short* wout_bf = (unsigned short*)(ws + 167772160ULL + 1572864ULL);
    float2* stats           = (float2*)(ws + 167772160ULL + 1572864ULL + 524288ULL);

    gn_stats  <<<B_ * G_, 256, 0, stream>>>(x, stats);
    cast_bf16 <<<C3_ * C_ / 1024, 256, 0, stream>>>(w_qkv, wqkv_bf);
    cast_bf16 <<<C_ * C_ / 1024, 256, 0, stream>>>(w_out, wout_bf);
    xnt_kernel<<<dim3(16, 8, B_), 256, 0, stream>>>(x, gamma, beta, stats, xnt);
    qkv_mfma  <<<dim3(8, 12, B_), 256, 0, stream>>>(wqkv_bf, xnt, b_qkv, Qb, Kb, Vb);
    scores_mfma<<<dim3(8, 8, B_), 256, 0, stream>>>(Qb, Kb, attn);
    softmax_rows<<<B_ * S_, 256, 0, stream>>>(attn);
    pv_mfma   <<<dim3(4, 8, B_), 256, 0, stream>>>(attn, Vb, Ob);
    out_mfma  <<<dim3(8, 4, B_), 256, 0, stream>>>(wout_bf, Ob, b_out, x, out);
}

// Round 3
// 416.152 us; speedup vs baseline: 4.6436x; 1.0398x over previous
//
#include <hip/hip_runtime.h>
#include <hip/hip_bf16.h>

#define B_    32
#define C_    512
#define S_    1024
#define G_    32
#define CPG_  16
#define C3_   1536
#define EPS_  1e-5f
#define SCALE_ 0.044194173824159216f   // 1/sqrt(512)

typedef __attribute__((ext_vector_type(4))) float  floatx4;
typedef __attribute__((ext_vector_type(8))) __bf16 bf16x8;

__device__ __forceinline__ float bf2f(unsigned short u) {
    union { unsigned int i; float f; } v; v.i = ((unsigned int)u) << 16; return v.f;
}
__device__ __forceinline__ unsigned short f2bf(float f) {
    union { float f; unsigned int i; } v; v.f = f;
    unsigned int r = v.i + 0x7fffu + ((v.i >> 16) & 1u);
    return (unsigned short)(r >> 16);
}

// direct global->LDS DMA, 16 bytes per lane. LDS dest = wave-uniform base + lane*16.
__device__ __forceinline__ void gl16(const unsigned short* g, unsigned short* l) {
    __builtin_amdgcn_global_load_lds(
        (const __attribute__((address_space(1))) unsigned int*)g,
        (__attribute__((address_space(3))) unsigned int*)l, 16, 0, 0);
}

// ---------------- group-norm stats ----------------
__global__ __launch_bounds__(256) void gn_stats(const float* __restrict__ x,
                                                float2* __restrict__ stats) {
    const size_t base = (size_t)blockIdx.x * (CPG_ * S_);
    const float4* xp = (const float4*)(x + base);
    float s = 0.f, ss = 0.f;
    for (int i = threadIdx.x; i < (CPG_ * S_) / 4; i += 256) {
        float4 v = xp[i];
        s  += v.x + v.y + v.z + v.w;
        ss += v.x * v.x + v.y * v.y + v.z * v.z + v.w * v.w;
    }
    #pragma unroll
    for (int o = 32; o; o >>= 1) { s += __shfl_down(s, o); ss += __shfl_down(ss, o); }
    __shared__ float a1[4], a2[4];
    const int wid = threadIdx.x >> 6, lane = threadIdx.x & 63;
    if (lane == 0) { a1[wid] = s; a2[wid] = ss; }
    __syncthreads();
    if (threadIdx.x == 0) {
        float S  = a1[0] + a1[1] + a1[2] + a1[3];
        float SS = a2[0] + a2[1] + a2[2] + a2[3];
        float mean = S * (1.f / 16384.f);
        float var  = SS * (1.f / 16384.f) - mean * mean;
        stats[blockIdx.x] = make_float2(mean, rsqrtf(var + EPS_));
    }
}

// ---------------- fp32 -> bf16 convert ----------------
__global__ __launch_bounds__(256) void cast_bf16(const float* __restrict__ src,
                                                 unsigned short* __restrict__ dst) {
    int i = (blockIdx.x * 256 + threadIdx.x) * 4;
    float4 v = *(const float4*)(src + i);
    ushort4 o; o.x = f2bf(v.x); o.y = f2bf(v.y); o.z = f2bf(v.z); o.w = f2bf(v.w);
    *(ushort4*)(dst + i) = o;
}

// ---------------- normalized x, transposed to [b][s][c], bf16 ----------------
__global__ __launch_bounds__(256) void xnt_kernel(const float* __restrict__ x,
                                                  const float* __restrict__ gamma,
                                                  const float* __restrict__ beta,
                                                  const float2* __restrict__ stats,
                                                  unsigned short* __restrict__ xnt) {
    const int b = blockIdx.z, c0 = blockIdx.y * 64, s0 = blockIdx.x * 64;
    __shared__ float tile[64][65];
    const float* xb = x + (size_t)b * (C_ * S_);
    const int t = threadIdx.x, tr = t >> 4, tc4 = (t & 15) * 4;
    #pragma unroll
    for (int i = 0; i < 4; i++) {
        int r = tr + i * 16;
        int c = c0 + r;
        float2 mv = stats[b * G_ + (c >> 4)];
        float a  = mv.y * gamma[c];
        float bb = beta[c] - mv.x * a;
        float4 v = *(const float4*)(xb + (size_t)c * S_ + s0 + tc4);
        tile[r][tc4 + 0] = a * v.x + bb;
        tile[r][tc4 + 1] = a * v.y + bb;
        tile[r][tc4 + 2] = a * v.z + bb;
        tile[r][tc4 + 3] = a * v.w + bb;
    }
    __syncthreads();
    unsigned short* xo = xnt + (size_t)b * (S_ * C_);
    #pragma unroll
    for (int i = 0; i < 4; i++) {
        int sr = tr + i * 16;
        ushort4 o4;
        o4.x = f2bf(tile[tc4 + 0][sr]);
        o4.y = f2bf(tile[tc4 + 1][sr]);
        o4.z = f2bf(tile[tc4 + 2][sr]);
        o4.w = f2bf(tile[tc4 + 3][sr]);
        *(ushort4*)(xo + (size_t)(s0 + sr) * C_ + c0 + tc4) = o4;
    }
}

// ---------------- MFMA 128x128 mainloop, global_load_lds staging ----------------
// C[m][n] = sum_k A[m][k]*B[n][k]; A,B bf16 K-contiguous, unpadded LDS [128][32].
// SWAP passes (B,A) to mfma so D rows index n, cols index m (free transpose).
template<bool SWAP>
__device__ __forceinline__ void mfma_loop(const unsigned short* __restrict__ Ag, int lda,
                                          const unsigned short* __restrict__ Bg, int ldb,
                                          int K, int m0, int n0,
                                          unsigned short* ldsA, unsigned short* ldsB,
                                          floatx4 (&acc)[4][4]) {
    const int t = threadIdx.x;
    const int lane = t & 63, wave = t >> 6;
    const int wr = (wave >> 1) * 64, wc = (wave & 1) * 64;
    const int lrow = lane & 15, lq = lane >> 4;
    // staging: wave w covers LDS bytes [w*1024, w*1024+1024) per issue.
    // lane l -> tile row (w*16 + l/4) (+64 for second issue), col (l&3)*8 ushorts.
    const int srow = wave * 16 + (lane >> 2);
    const int scol = (lane & 3) * 8;
    unsigned short* lA0 = ldsA + wave * 512;
    unsigned short* lA1 = ldsA + 2048 + wave * 512;
    unsigned short* lB0 = ldsB + wave * 512;
    unsigned short* lB1 = ldsB + 2048 + wave * 512;
    const unsigned short* gA0 = Ag + (size_t)(m0 + srow) * lda + scol;
    const unsigned short* gA1 = gA0 + (size_t)64 * lda;
    const unsigned short* gB0 = Bg + (size_t)(n0 + srow) * ldb + scol;
    const unsigned short* gB1 = gB0 + (size_t)64 * ldb;
    for (int k0 = 0; k0 < K; k0 += 32) {
        gl16(gA0 + k0, lA0);
        gl16(gA1 + k0, lA1);
        gl16(gB0 + k0, lB0);
        gl16(gB1 + k0, lB1);
        __syncthreads();
        bf16x8 af[4], bfr[4];
        #pragma unroll
        for (int i = 0; i < 4; i++) {
            af[i]  = *(const bf16x8*)(ldsA + (wr + i * 16 + lrow) * 32 + lq * 8);
            bfr[i] = *(const bf16x8*)(ldsB + (wc + i * 16 + lrow) * 32 + lq * 8);
        }
        #pragma unroll
        for (int i = 0; i < 4; i++)
            #pragma unroll
            for (int j = 0; j < 4; j++) {
                if (SWAP)
                    acc[i][j] = __builtin_amdgcn_mfma_f32_16x16x32_bf16(bfr[j], af[i], acc[i][j], 0, 0, 0);
                else
                    acc[i][j] = __builtin_amdgcn_mfma_f32_16x16x32_bf16(af[i], bfr[j], acc[i][j], 0, 0, 0);
            }
        __syncthreads();
    }
}

#define GEMM_PROLOGUE                                                   \
    __shared__ __align__(16) unsigned short ldsA[128 * 32];             \
    __shared__ __align__(16) unsigned short ldsB[128 * 32];             \
    const int b = blockIdx.z;                                           \
    const int m0 = blockIdx.y * 128, n0 = blockIdx.x * 128;             \
    const int t = threadIdx.x, lane = t & 63, wave = t >> 6;            \
    const int wr = (wave >> 1) * 64, wc = (wave & 1) * 64;              \
    const int lrow = lane & 15, lq = lane >> 4;                         \
    floatx4 acc[4][4];                                                  \
    _Pragma("unroll") for (int i = 0; i < 4; i++)                       \
        _Pragma("unroll") for (int j = 0; j < 4; j++)                   \
            acc[i][j] = (floatx4){0.f, 0.f, 0.f, 0.f};

// ---------------- QKV projection ----------------
// A = wqkv_bf [1536][512], B = xnt[b] [1024][512].
// m-tiles 0-7 -> Q,K stored [s][c] (transposed write), 8-11 -> V[c][s] (SWAP).
__global__ __launch_bounds__(256) void qkv_mfma(const unsigned short* __restrict__ wbf,
                                                const unsigned short* __restrict__ xnt,
                                                const float* __restrict__ bias,
                                                unsigned short* __restrict__ Qb,
                                                unsigned short* __restrict__ Kb,
                                                unsigned short* __restrict__ Vb) {
    GEMM_PROLOGUE
    const unsigned short* Bg = xnt + (size_t)b * (S_ * C_);
    if (m0 < 1024) {
        mfma_loop<false>(wbf, C_, Bg, C_, C_, m0, n0, ldsA, ldsB, acc);
        unsigned short* dst = (m0 < 512 ? Qb : Kb) + (size_t)b * (S_ * C_);
        const int osec = (m0 < 512) ? 0 : 512;
        #pragma unroll
        for (int i = 0; i < 4; i++)
            #pragma unroll
            for (int j = 0; j < 4; j++) {
                int oabs = m0 + wr + i * 16 + lq * 4;
                int s    = n0 + wc + j * 16 + lrow;
                float4 bi = *(const float4*)(bias + oabs);
                floatx4 v = acc[i][j];
                ushort4 o4;
                o4.x = f2bf(v[0] + bi.x); o4.y = f2bf(v[1] + bi.y);
                o4.z = f2bf(v[2] + bi.z); o4.w = f2bf(v[3] + bi.w);
                *(ushort4*)(dst + (size_t)s * C_ + (oabs - osec)) = o4;
            }
    } else {
        mfma_loop<true>(wbf, C_, Bg, C_, C_, m0, n0, ldsA, ldsB, acc);
        unsigned short* dst = Vb + (size_t)b * (C_ * S_);
        #pragma unroll
        for (int i = 0; i < 4; i++)
            #pragma unroll
            for (int j = 0; j < 4; j++) {
                int c  = m0 - 1024 + wr + i * 16 + lrow;   // cols index m (o)
                int sb = n0 + wc + j * 16 + lq * 4;        // rows index n (s)
                float bi = bias[1024 + c];
                floatx4 v = acc[i][j];
                ushort4 o4;
                o4.x = f2bf(v[0] + bi); o4.y = f2bf(v[1] + bi);
                o4.z = f2bf(v[2] + bi); o4.w = f2bf(v[3] + bi);
                *(ushort4*)(dst + (size_t)c * S_ + sb) = o4;
            }
    }
}

// ---------------- scores: attn[i][j] = SCALE * Q[i][:] . K[j][:] ----------------
__global__ __launch_bounds__(256) void scores_mfma(const unsigned short* __restrict__ Qb,
                                                   const unsigned short* __restrict__ Kb,
                                                   unsigned short* __restrict__ attn) {
    GEMM_PROLOGUE
    const unsigned short* Ag = Qb + (size_t)b * (S_ * C_);
    const unsigned short* Bg = Kb + (size_t)b * (S_ * C_);
    mfma_loop<false>(Ag, C_, Bg, C_, C_, m0, n0, ldsA, ldsB, acc);
    unsigned short* ap = attn + (size_t)b * (S_ * S_);
    #pragma unroll
    for (int i = 0; i < 4; i++)
        #pragma unroll
        for (int j = 0; j < 4; j++) {
            int jj = n0 + wc + j * 16 + lrow;
            int ib = m0 + wr + i * 16 + lq * 4;
            floatx4 v = acc[i][j];
            #pragma unroll
            for (int r = 0; r < 4; r++)
                ap[(size_t)(ib + r) * S_ + jj] = f2bf(v[r] * SCALE_);
        }
}

// ---------------- softmax rows (in place bf16) ----------------
__global__ __launch_bounds__(256) void softmax_rows(unsigned short* __restrict__ attn) {
    unsigned short* p = attn + (size_t)blockIdx.x * S_;
    const int t = threadIdx.x;
    ushort4 uv = *(const ushort4*)(p + t * 4);
    float v0 = bf2f(uv.x), v1 = bf2f(uv.y), v2 = bf2f(uv.z), v3 = bf2f(uv.w);
    float m = fmaxf(fmaxf(v0, v1), fmaxf(v2, v3));
    #pragma unroll
    for (int o = 32; o; o >>= 1) m = fmaxf(m, __shfl_down(m, o));
    __shared__ float lm[4], lsum[4];
    const int wid = t >> 6, lane = t & 63;
    if (lane == 0) lm[wid] = m;
    __syncthreads();
    m = fmaxf(fmaxf(lm[0], lm[1]), fmaxf(lm[2], lm[3]));
    float e0 = __expf(v0 - m), e1 = __expf(v1 - m), e2 = __expf(v2 - m), e3 = __expf(v3 - m);
    float s = e0 + e1 + e2 + e3;
    #pragma unroll
    for (int o = 32; o; o >>= 1) s += __shfl_down(s, o);
    if (lane == 0) lsum[wid] = s;
    __syncthreads();
    float T = lsum[0] + lsum[1] + lsum[2] + lsum[3];
    float r = __frcp_rn(T);
    ushort4 ov;
    ov.x = f2bf(e0 * r); ov.y = f2bf(e1 * r); ov.z = f2bf(e2 * r); ov.w = f2bf(e3 * r);
    *(ushort4*)(p + t * 4) = ov;
}

// ---------------- PV: O[i][c] = sum_j P[i][j] V[c][j] ----------------
__global__ __launch_bounds__(256) void pv_mfma(const unsigned short* __restrict__ attn,
                                               const unsigned short* __restrict__ Vb,
                                               unsigned short* __restrict__ Ob) {
    GEMM_PROLOGUE
    const unsigned short* Ag = attn + (size_t)b * (S_ * S_);
    const unsigned short* Bg = Vb + (size_t)b * (C_ * S_);
    mfma_loop<false>(Ag, S_, Bg, S_, S_, m0, n0, ldsA, ldsB, acc);
    unsigned short* op = Ob + (size_t)b * (S_ * C_);
    #pragma unroll
    for (int i = 0; i < 4; i++)
        #pragma unroll
        for (int j = 0; j < 4; j++) {
            int cc = n0 + wc + j * 16 + lrow;
            int ib = m0 + wr + i * 16 + lq * 4;
            floatx4 v = acc[i][j];
            #pragma unroll
            for (int r = 0; r < 4; r++)
                op[(size_t)(ib + r) * C_ + cc] = f2bf(v[r]);
        }
}

// ---------------- out projection + bias + residual ----------------
__global__ __launch_bounds__(256) void out_mfma(const unsigned short* __restrict__ wbf,
                                                const unsigned short* __restrict__ Ob,
                                                const float* __restrict__ bias,
                                                const float* __restrict__ x,
                                                float* __restrict__ out) {
    GEMM_PROLOGUE
    const unsigned short* Bg = Ob + (size_t)b * (S_ * C_);
    mfma_loop<false>(wbf, C_, Bg, C_, C_, m0, n0, ldsA, ldsB, acc);
    const float* xb = x + (size_t)b * (C_ * S_);
    float* ob = out + (size_t)b * (C_ * S_);
    #pragma unroll
    for (int i = 0; i < 4; i++)
        #pragma unroll
        for (int j = 0; j < 4; j++) {
            int obase = m0 + wr + i * 16 + lq * 4;
            int s     = n0 + wc + j * 16 + lrow;
            float4 bi = *(const float4*)(bias + obase);
            floatx4 v = acc[i][j];
            float bb[4] = {bi.x, bi.y, bi.z, bi.w};
            #pragma unroll
            for (int r = 0; r < 4; r++) {
                size_t idx = (size_t)(obase + r) * S_ + s;
                ob[idx] = v[r] + bb[r] + xb[idx];
            }
        }
}

// ---------------- launch ----------------
extern "C" void kernel_launch(void* const* d_in, const int* in_sizes, int n_in,
                              void* d_out, int out_size, void* d_ws, size_t ws_size,
                              hipStream_t stream) {
    const float* x      = (const float*)d_in[0];
    const float* gamma  = (const float*)d_in[1];
    const float* beta   = (const float*)d_in[2];
    const float* w_qkv  = (const float*)d_in[3];
    const float* b_qkv  = (const float*)d_in[4];
    const float* w_out  = (const float*)d_in[5];
    const float* b_out  = (const float*)d_in[6];
    float* out          = (float*)d_out;

    char* ws = (char*)d_ws;
    // layout (bytes), with safe aliasing (all kernels stream-ordered):
    //   Qb   [b][1024][512] bf16 @ 0         (32 MB)  -- dead after scores
    //   Kb   [b][1024][512] bf16 @ 32 MB     (32 MB)
    //   Vb   [b][512][1024] bf16 @ 64 MB     (32 MB)
    //   xnt  [b][1024][512] bf16 @ 96 MB     (32 MB)  -- dead after qkv
    //   attn [b][1024][1024] bf16 @ 96 MB    (64 MB)  -- aliases xnt
    //   Ob   [b][1024][512] bf16 @ 0         (32 MB)  -- aliases Qb
    //   wqkv_bf @ 160 MB, wout_bf, stats     (~2.1 MB)
    unsigned short* Qb   = (unsigned short*)(ws);
    unsigned short* Kb   = (unsigned short*)(ws + 33554432ULL);
    unsigned short* Vb   = (unsigned short*)(ws + 67108864ULL);
    unsigned short* xnt  = (unsigned short*)(ws + 100663296ULL);
    unsigned short* attn = (unsigned short*)(ws + 100663296ULL);
    unsigned short* Ob   = (unsigned short*)(ws);
    unsigned short* wqkv_bf = (unsigned short*)(ws + 167772160ULL);
    unsigned short* wout_bf = (unsigned short*)(ws + 167772160ULL + 1572864ULL);
    float2* stats           = (float2*)(ws + 167772160ULL + 1572864ULL + 524288ULL);

    gn_stats  <<<B_ * G_, 256, 0, stream>>>(x, stats);
    cast_bf16 <<<C3_ * C_ / 1024, 256, 0, stream>>>(w_qkv, wqkv_bf);
    cast_bf16 <<<C_ * C_ / 1024, 256, 0, stream>>>(w_out, wout_bf);
    xnt_kernel<<<dim3(16, 8, B_), 256, 0, stream>>>(x, gamma, beta, stats, xnt);
    qkv_mfma  <<<dim3(8, 12, B_), 256, 0, stream>>>(wqkv_bf, xnt, b_qkv, Qb, Kb, Vb);
    scores_mfma<<<dim3(8, 8, B_), 256, 0, stream>>>(Qb, Kb, attn);
    softmax_rows<<<B_ * S_, 256, 0, stream>>>(attn);
    pv_mfma   <<<dim3(4, 8, B_), 256, 0, stream>>>(attn, Vb, Ob);
    out_mfma  <<<dim3(8, 4, B_), 256, 0, stream>>>(wout_bf, Ob, b_out, x, out);
}